// Round 1
// baseline (335.436 us; speedup 1.0000x reference)
//
#include <hip/hip_runtime.h>
#include <math.h>

// Problem constants (match reference)
#define CUTOFF_F 10.0f
#define PI_OVER_CUTOFF 0.31415926535897931f  // pi/10
#define KID 32   // id-bucket capacity (ints); overflow -> fp32 atomics into aggr

// ===========================================================================
// Primary path: scatter EDGE IDS only (4B, cache-merged writes), gather raw
// features in node_fused in fp32. Edges with coeff==0 (d > CUTOFF) dropped.
// Overflow (slot >= KID, ~never at Poisson(13.3)) -> fp32 atomics into aggr.
// ===========================================================================
__global__ __launch_bounds__(256) void fill_ids(
    const float* __restrict__ gds,
    const int* __restrict__ eidx,
    const float* __restrict__ edge_sca,
    const float* __restrict__ edge_vec,
    int* __restrict__ count,
    int* __restrict__ bucket,   // [N*KID] edge ids
    float* __restrict__ aggr,   // [N*16] overflow accumulator (zeroed)
    int E)
{
    int e = blockIdx.x * blockDim.x + threadIdx.x;
    if (e >= E) return;

    float d = gds[e];
    // coeff == 0 outside [0, CUTOFF]: contributes nothing -> drop before ticket
    if (d > CUTOFF_F || d < 0.0f) return;

    int src = eidx[e];
    int slot = atomicAdd(&count[src], 1);
    if (slot < KID) {
        bucket[(size_t)src * KID + slot] = e;
    } else {
        float c = 0.5f * (__cosf(d * PI_OVER_CUTOFF) + 1.0f);
        const float* es = edge_sca + (size_t)e * 6;
        const float* ev = edge_vec + (size_t)e * 9;
        float* base = aggr + (size_t)src * 16;
#pragma unroll
        for (int i = 0; i < 6; ++i) atomicAdd(base + i, c * es[i]);
        atomicAdd(base + 6, c);
#pragma unroll
        for (int i = 0; i < 9; ++i) atomicAdd(base + 7 + i, c * ev[i]);
    }
}

// ===========================================================================
// Mode 0 fallback: pure fp32 atomic aggregation (tiny workspace)
// ===========================================================================
__global__ __launch_bounds__(256) void edge_aggregate(
    const float* __restrict__ edge_sca, const float* __restrict__ edge_vec,
    const float* __restrict__ gds, const int* __restrict__ eidx,
    float* __restrict__ aggr, int E)
{
    int e = blockIdx.x * blockDim.x + threadIdx.x;
    if (e >= E) return;
    int src = eidx[e];
    float d = gds[e];
    float coeff = 0.0f;
    if (d >= 0.0f && d <= CUTOFF_F)
        coeff = 0.5f * (__cosf(d * PI_OVER_CUTOFF) + 1.0f);
    float* base = aggr + (size_t)src * 16;
    const float* es = edge_sca + (size_t)e * 6;
    const float* ev = edge_vec + (size_t)e * 9;
#pragma unroll
    for (int c = 0; c < 6; ++c) atomicAdd(base + c, coeff * es[c]);
    atomicAdd(base + 6, coeff);
#pragma unroll
    for (int k = 0; k < 9; ++k) atomicAdd(base + 7 + k, coeff * ev[k]);
}

// ===========================================================================
// Fused node kernel. mode: 4 = id-bucket gather (+aggr overflow), 0 = aggr only.
// 16 lanes per node, 16 nodes per 256-block.
// ===========================================================================
__global__ __launch_bounds__(256) void node_fused(
    const float* __restrict__ node_sca,
    const float* __restrict__ node_vec,
    const float* __restrict__ edge_sca,
    const float* __restrict__ edge_vec,
    const float* __restrict__ gds,
    const int* __restrict__ count,
    const int* __restrict__ bucket,      // mode 4: edge ids
    const float* __restrict__ aggr,      // mode 0 / mode 4 overflow
    const float* __restrict__ W_nss, const float* __restrict__ b_nss,
    const float* __restrict__ W_ess, const float* __restrict__ b_ess,
    const float* __restrict__ W_nsv, const float* __restrict__ b_nsv,
    const float* __restrict__ W_esv, const float* __restrict__ b_esv,
    const float* __restrict__ W_nvv, const float* __restrict__ W_evv,
    const float* __restrict__ W_lv,  const float* __restrict__ W_lv2,
    const float* __restrict__ W_ls,
    const float* __restrict__ W_gate, const float* __restrict__ b_gate,
    const float* __restrict__ W_dir,
    float* __restrict__ out,
    int N, int mode)
{
    // ---- weights in LDS ----
    __shared__ float sW_nss[64],  sb_nss[16];
    __shared__ float sW_ess[96],  sb_ess[16];
    __shared__ float sW_nsv[64],  sb_nsv[16];
    __shared__ float sW_esv[96],  sb_esv[16];
    __shared__ float sW_nvv[48],  sW_evv[48];
    __shared__ float sW_lv[256],  sW_lv2[256];
    __shared__ float sW_ls[512];
    __shared__ float sW_gate[256], sb_gate[16];
    __shared__ float sW_dir[256];

    // ---- per-node scratch (odd node-strides -> no bank conflicts) ----
    __shared__ float s_in  [16 * 33];
    __shared__ float s_avec[16 * 49];
    __shared__ float s_cat [16 * 33];
    __shared__ float s_vint[16 * 49];
    __shared__ float s_osca[16 * 17];
    __shared__ float s_ovec[16 * 49];

    // ---- id-gather staging: [slot-of-s][node] padded layout (*17) ----
    __shared__ int   s_eid[KID * 17];
    __shared__ float s_ec [KID * 17];

    const int t = threadIdx.x;
    {
        for (int i = t; i < 64;  i += 256) { sW_nss[i] = W_nss[i]; sW_nsv[i] = W_nsv[i]; }
        for (int i = t; i < 96;  i += 256) { sW_ess[i] = W_ess[i]; sW_esv[i] = W_esv[i]; }
        for (int i = t; i < 48;  i += 256) { sW_nvv[i] = W_nvv[i]; sW_evv[i] = W_evv[i]; }
        for (int i = t; i < 256; i += 256) {
            sW_lv[i]   = W_lv[i];
            sW_lv2[i]  = W_lv2[i];
            sW_gate[i] = W_gate[i];
            sW_dir[i]  = W_dir[i];
        }
        for (int i = t; i < 512; i += 256) sW_ls[i] = W_ls[i];
        if (t < 16) {
            sb_nss[t]  = b_nss[t];
            sb_ess[t]  = b_ess[t];
            sb_nsv[t]  = b_nsv[t];
            sb_esv[t]  = b_esv[t];
            sb_gate[t] = b_gate[t];
        }
    }

    const int slot = t >> 4;
    const int o    = t & 15;
    const int n    = blockIdx.x * 16 + slot;
    const bool valid = (n < N);

    if (valid) {
        if (o < 4) s_in[slot * 33 + o]     = node_sca[(size_t)n * 4 + o];
        if (o < 9) s_in[slot * 33 + 4 + o] = node_vec[(size_t)n * 9 + o];
    }

    if (mode == 4) {
        int cnt = 0;
        if (valid) {
            cnt = count[n];
            if (cnt > KID) cnt = KID;
            // stage ids + per-edge coeff (computed once per edge, not per lane)
            const int* bk = bucket + (size_t)n * KID;
            for (int s = o; s < cnt; s += 16) {
                int e = bk[s];                 // coalesced: 16 lanes read 64B
                float d = gds[e];              // random 4B; gds is 6.4MB (L2-hot)
                s_eid[s * 17 + slot] = e;
                s_ec [s * 17 + slot] = 0.5f * (__cosf(d * PI_OVER_CUTOFF) + 1.0f);
            }
        }
        __syncthreads();   // ids/coeffs written by other lanes of this group
        if (valid) {
            float acc = aggr[(size_t)n * 16 + o];   // overflow (zero if none)
            const float* fsrc = (o < 6) ? edge_sca : edge_vec;
            const int    st   = (o < 6) ? 6 : 9;
            const int    off  = (o < 6) ? o : (o - 7);
            for (int s = 0; s < cnt; ++s) {
                int   e = s_eid[s * 17 + slot];     // broadcast within group
                float c = s_ec [s * 17 + slot];
                float f = (o == 6) ? 1.0f : fsrc[(size_t)e * st + off];
                acc += c * f;
            }
            s_in[slot * 33 + 13 + o] = acc;
        }
    } else {
        if (valid) s_in[slot * 33 + 13 + o] = aggr[(size_t)n * 16 + o];
    }
    __syncthreads();

    const float* in = s_in + slot * 33;

    float nss = sb_nss[o], nsv = sb_nsv[o];
#pragma unroll
    for (int c = 0; c < 4; ++c) {
        float x = in[c];
        nss += x * sW_nss[c * 16 + o];
        nsv += x * sW_nsv[c * 16 + o];
    }
    float nvv0 = 0.f, nvv1 = 0.f, nvv2 = 0.f;
#pragma unroll
    for (int c = 0; c < 3; ++c) {
        float w = sW_nvv[c * 16 + o];
        nvv0 += in[4 + c * 3 + 0] * w;
        nvv1 += in[4 + c * 3 + 1] * w;
        nvv2 += in[4 + c * 3 + 2] * w;
    }
    float cc = in[19];
    float es = cc * sb_ess[o], ev = cc * sb_esv[o];
#pragma unroll
    for (int c = 0; c < 6; ++c) {
        float a = in[13 + c];
        es += a * sW_ess[c * 16 + o];
        ev += a * sW_esv[c * 16 + o];
    }
    float EV0 = 0.f, EV1 = 0.f, EV2 = 0.f;
#pragma unroll
    for (int c = 0; c < 3; ++c) {
        float w = sW_evv[c * 16 + o];
        EV0 += in[20 + c * 3 + 0] * w;
        EV1 += in[20 + c * 3 + 1] * w;
        EV2 += in[20 + c * 3 + 2] * w;
    }

    float asca = nss * es;
    float av0 = nvv0 * ev + nsv * EV0;
    float av1 = nvv1 * ev + nsv * EV1;
    float av2 = nvv2 * ev + nsv * EV2;
    s_avec[slot * 49 + o * 3 + 0] = av0;
    s_avec[slot * 49 + o * 3 + 1] = av1;
    s_avec[slot * 49 + o * 3 + 2] = av2;
    s_cat[slot * 33 + 16 + o] = asca;
    __syncthreads();

    float vi0 = 0.f, vi1 = 0.f, vi2 = 0.f;
#pragma unroll
    for (int c = 0; c < 16; ++c) {
        float w = sW_lv[c * 16 + o];
        const float* a = &s_avec[slot * 49 + c * 3];
        vi0 += a[0] * w; vi1 += a[1] * w; vi2 += a[2] * w;
    }
    float vnorm = sqrtf(vi0 * vi0 + vi1 * vi1 + vi2 * vi2);
    s_vint[slot * 49 + o * 3 + 0] = vi0;
    s_vint[slot * 49 + o * 3 + 1] = vi1;
    s_vint[slot * 49 + o * 3 + 2] = vi2;
    s_cat[slot * 33 + o] = vnorm;
    __syncthreads();

    float osca = 0.f;
#pragma unroll
    for (int c = 0; c < 32; ++c)
        osca += s_cat[slot * 33 + c] * sW_ls[c * 16 + o];
    float ov0 = 0.f, ov1 = 0.f, ov2 = 0.f;
#pragma unroll
    for (int c = 0; c < 16; ++c) {
        float w = sW_lv2[c * 16 + o];
        const float* a = &s_vint[slot * 49 + c * 3];
        ov0 += a[0] * w; ov1 += a[1] * w; ov2 += a[2] * w;
    }
    s_osca[slot * 17 + o] = osca;
    __syncthreads();

    float g = sb_gate[o];
#pragma unroll
    for (int c = 0; c < 16; ++c)
        g += s_osca[slot * 17 + c] * sW_gate[c * 16 + o];
    g = 1.0f / (1.0f + __expf(-g));
    ov0 *= g; ov1 *= g; ov2 *= g;
    s_ovec[slot * 49 + o * 3 + 0] = ov0;
    s_ovec[slot * 49 + o * 3 + 1] = ov1;
    s_ovec[slot * 49 + o * 3 + 2] = ov2;
    __syncthreads();

    float dv0 = 0.f, dv1 = 0.f, dv2 = 0.f;
#pragma unroll
    for (int c = 0; c < 16; ++c) {
        float w = sW_dir[c * 16 + o];
        const float* a = &s_ovec[slot * 49 + c * 3];
        dv0 += a[0] * w; dv1 += a[1] * w; dv2 += a[2] * w;
    }
    float dot = ov0 * dv0 + ov1 * dv1 + ov2 * dv2;
    if (dot < 0.0f) {
        float dn = dv0 * dv0 + dv1 * dv1 + dv2 * dv2;
        float f = 0.8f * dot / (dn + 1e-6f);
        ov0 -= f * dv0; ov1 -= f * dv1; ov2 -= f * dv2;
    }

    if (valid) {
        float so = (osca >= 0.0f) ? osca : 0.01f * osca;
        out[(size_t)n * 16 + o] = so;
        size_t vb = (size_t)N * 16 + (size_t)n * 48 + (size_t)o * 3;
        out[vb + 0] = ov0;
        out[vb + 1] = ov1;
        out[vb + 2] = ov2;
    }
}

extern "C" void kernel_launch(void* const* d_in, const int* in_sizes, int n_in,
                              void* d_out, int out_size, void* d_ws, size_t ws_size,
                              hipStream_t stream)
{
    const float* node_sca = (const float*)d_in[0];
    const float* node_vec = (const float*)d_in[1];
    const float* edge_sca = (const float*)d_in[2];
    const float* edge_vec = (const float*)d_in[3];
    const float* gds      = (const float*)d_in[4];
    const int*   eidx     = (const int*)d_in[5];

    const int N = in_sizes[0] / 4;   // node_sca is [N,4]
    const int E = in_sizes[4];       // gds_dist is [E]

    // ---- mode-4 layout: [count N ints][aggr N*16 floats][bucket N*KID ints]
    int*   count4  = (int*)d_ws;
    float* aggr4   = (float*)(count4 + N);
    int*   bucket4 = (int*)(aggr4 + (size_t)N * 16);
    size_t need4   = (size_t)N * 4 + (size_t)N * 64 + (size_t)N * KID * 4;

    // ---- mode-0 layout: [aggr N*16 floats]
    float* aggr0  = (float*)d_ws;
    size_t need0  = (size_t)N * 64;

    if (ws_size >= need4) {
        // zero count + overflow aggr in one memset (adjacent)
        hipMemsetAsync(count4, 0, (size_t)N * 4 + (size_t)N * 64, stream);
        fill_ids<<<(E + 255) / 256, 256, 0, stream>>>(
            gds, eidx, edge_sca, edge_vec, count4, bucket4, aggr4, E);
        node_fused<<<(N + 15) / 16, 256, 0, stream>>>(
            node_sca, node_vec, edge_sca, edge_vec, gds,
            count4, bucket4, aggr4,
            (const float*)d_in[6],  (const float*)d_in[7],
            (const float*)d_in[8],  (const float*)d_in[9],
            (const float*)d_in[10], (const float*)d_in[11],
            (const float*)d_in[12], (const float*)d_in[13],
            (const float*)d_in[14], (const float*)d_in[15],
            (const float*)d_in[16], (const float*)d_in[17],
            (const float*)d_in[18],
            (const float*)d_in[19], (const float*)d_in[20],
            (const float*)d_in[21],
            (float*)d_out, N, 4);
        return;
    }

    // fallback: fp32 atomic aggregation
    (void)need0;
    hipMemsetAsync(aggr0, 0, (size_t)N * 64, stream);
    edge_aggregate<<<(E + 255) / 256, 256, 0, stream>>>(
        edge_sca, edge_vec, gds, eidx, aggr0, E);
    node_fused<<<(N + 15) / 16, 256, 0, stream>>>(
        node_sca, node_vec, edge_sca, edge_vec, gds,
        (const int*)d_ws, (const int*)d_ws, aggr0,
        (const float*)d_in[6],  (const float*)d_in[7],
        (const float*)d_in[8],  (const float*)d_in[9],
        (const float*)d_in[10], (const float*)d_in[11],
        (const float*)d_in[12], (const float*)d_in[13],
        (const float*)d_in[14], (const float*)d_in[15],
        (const float*)d_in[16], (const float*)d_in[17],
        (const float*)d_in[18],
        (const float*)d_in[19], (const float*)d_in[20],
        (const float*)d_in[21],
        (float*)d_out, N, 0);
}